// Round 2
// baseline (1179.032 us; speedup 1.0000x reference)
//
#include <hip/hip_runtime.h>

#define H 128

typedef float v4f __attribute__((ext_vector_type(4)));
typedef short v8s __attribute__((ext_vector_type(8)));

// ---------------- bf16 helpers ----------------

__device__ inline unsigned short bf16_rne(float x) {
  unsigned u = __builtin_bit_cast(unsigned, x);
  unsigned r = u + 0x7FFF + ((u >> 16) & 1);
  return (unsigned short)(r >> 16);
}

__device__ inline void split_bf16(float x, unsigned short& hi, unsigned short& lo) {
  unsigned u = __builtin_bit_cast(unsigned, x);
  unsigned r = u + 0x7FFF + ((u >> 16) & 1);  // RNE round to bf16
  hi = (unsigned short)(r >> 16);
  float hf = __builtin_bit_cast(float, r & 0xFFFF0000u);
  float d = x - hf;
  unsigned ud = __builtin_bit_cast(unsigned, d);
  unsigned rd = ud + 0x7FFF + ((ud >> 16) & 1);
  lo = (unsigned short)(rd >> 16);
}

// ---------------- CSR build (unchanged) ----------------

__global__ void hist_kernel(const int* __restrict__ dst, int* __restrict__ deg, int E) {
  int e = blockIdx.x * 256 + threadIdx.x;
  if (e < E) atomicAdd(&deg[dst[e]], 1);
}

__global__ __launch_bounds__(1024) void scan1_kernel(const int* __restrict__ deg,
                                                     int* __restrict__ incl,
                                                     int* __restrict__ blk_sum, int N) {
  __shared__ int lds[1024];
  int t = threadIdx.x;
  int i = blockIdx.x * 1024 + t;
  int v = (i < N) ? deg[i] : 0;
  lds[t] = v;
  __syncthreads();
  for (int off = 1; off < 1024; off <<= 1) {
    int x = (t >= off) ? lds[t - off] : 0;
    __syncthreads();
    lds[t] += x;
    __syncthreads();
  }
  if (i < N) incl[i] = lds[t];
  if (t == 1023) blk_sum[blockIdx.x] = lds[1023];
}

__global__ void scan2_kernel(const int* __restrict__ blk_sum, int* __restrict__ blk_off, int B) {
  __shared__ int lds[256];
  int t = threadIdx.x;
  int v = (t < B) ? blk_sum[t] : 0;
  lds[t] = v;
  __syncthreads();
  for (int off = 1; off < 256; off <<= 1) {
    int x = (t >= off) ? lds[t - off] : 0;
    __syncthreads();
    lds[t] += x;
    __syncthreads();
  }
  blk_off[t] = lds[t] - v;  // exclusive scan of block sums
}

__global__ void rowstart_kernel(const int* __restrict__ incl, const int* __restrict__ deg,
                                const int* __restrict__ blk_off, int* __restrict__ row_start,
                                int N) {
  int i = blockIdx.x * 256 + threadIdx.x;
  if (i < N) row_start[i] = blk_off[i >> 10] + incl[i] - deg[i];
}

__global__ void fill_kernel(const int* __restrict__ src, const int* __restrict__ dst,
                            const int* __restrict__ row_start, int* __restrict__ cursor,
                            int* __restrict__ csr_src, int E) {
  int e = blockIdx.x * 256 + threadIdx.x;
  if (e < E) {
    int d = dst[e];
    int p = atomicAdd(&cursor[d], 1);
    csr_src[row_start[d] + p] = src[e];
  }
}

// ---------------- feature gather: emb -> bf16 hi/lo planes ----------------

__global__ void gather_kernel(const float* __restrict__ emb, const int* __restrict__ node_id,
                              unsigned short* __restrict__ h_hi, unsigned short* __restrict__ h_lo,
                              int N) {
  int i = blockIdx.x * 256 + threadIdx.x;
  if (i < N * 32) {
    int n = i >> 5, g = i & 31;
    float4 v = ((const float4*)emb)[(size_t)node_id[n] * 32 + g];
    float vv[4] = {v.x, v.y, v.z, v.w};
    unsigned short hs[4], ls[4];
#pragma unroll
    for (int k = 0; k < 4; ++k) split_bf16(vv[k], hs[k], ls[k]);
    size_t base = (size_t)n * H + g * 4;
    *(uint2*)(h_hi + base) = make_uint2((unsigned)hs[0] | ((unsigned)hs[1] << 16),
                                        (unsigned)hs[2] | ((unsigned)hs[3] << 16));
    *(uint2*)(h_lo + base) = make_uint2((unsigned)ls[0] | ((unsigned)ls[1] << 16),
                                        (unsigned)ls[2] | ((unsigned)ls[3] << 16));
  }
}

// ---------------- weight pre-split into MFMA-frag-ordered planes ----------------
// Frag order per plane (16384 shorts): e = c*2048 + kb*512 + q*128 + m*8 + j
// holds W[col = c*16+m][k = kb*32 + q*8 + j]. Buffer layout:
// Wf[layer][side l/r][hi,lo][16384], layer stride 65536 shorts.

__global__ void wsplit_kernel(const float* __restrict__ W0, const float* __restrict__ W1,
                              const float* __restrict__ W2, const float* __restrict__ W3,
                              const float* __restrict__ W4, const float* __restrict__ W5,
                              unsigned short* __restrict__ Wf) {
  int idx = blockIdx.x * 256 + threadIdx.x;  // 0..98303 (6 planes x 16384)
  int sp = idx >> 14;                        // {W1l,W1r,W2l,W2r,W3l,W3r}
  int e = idx & 16383;
  const float* src = sp == 0 ? W0 : sp == 1 ? W1 : sp == 2 ? W2
                   : sp == 3 ? W3 : sp == 4 ? W4 : W5;
  int c = e >> 11;
  int kb = (e >> 9) & 3;
  int qq = (e >> 7) & 3;
  int mm = (e >> 3) & 15;
  int j = e & 7;
  int col = c * 16 + mm;
  int k = kb * 32 + qq * 8 + j;
  unsigned short hi, lo;
  split_bf16(src[col * H + k], hi, lo);
  size_t base = (size_t)(sp >> 1) * 65536 + (size_t)(sp & 1) * 32768 + e;
  Wf[base] = hi;          // hi plane
  Wf[base + 16384] = lo;  // lo plane
}

// ---------------- mean aggregation (CSR, bf16 gather, split-plane output) ----------------

__global__ __launch_bounds__(256) void aggregate_kernel(const unsigned short* __restrict__ hb,
                                                        const int* __restrict__ csr_src,
                                                        const int* __restrict__ row_start,
                                                        const int* __restrict__ deg,
                                                        unsigned short* __restrict__ a_hi,
                                                        unsigned short* __restrict__ a_lo, int N) {
  int node = blockIdx.x * 4 + (threadIdx.x >> 6);
  if (node >= N) return;
  int lane = threadIdx.x & 63;
  int qe = lane >> 4;  // edge slot 0..3
  int cl = lane & 15;  // channel group: channels cl*8 .. cl*8+7
  const uint4* __restrict__ h16 = (const uint4*)hb;

  int start = row_start[node];
  int d = deg[node];

  float acc[8] = {0.f, 0.f, 0.f, 0.f, 0.f, 0.f, 0.f, 0.f};

  auto accum = [&](uint4 u) {
    unsigned uu[4] = {u.x, u.y, u.z, u.w};
#pragma unroll
    for (int j = 0; j < 4; ++j) {
      acc[2 * j] += __builtin_bit_cast(float, uu[j] << 16);
      acc[2 * j + 1] += __builtin_bit_cast(float, uu[j] & 0xFFFF0000u);
    }
  };

  int e = qe;
  for (; e + 4 < d; e += 8) {
    int s0 = csr_src[start + e];
    int s1 = csr_src[start + e + 4];
    uint4 u0 = h16[(size_t)s0 * 16 + cl];
    uint4 u1 = h16[(size_t)s1 * 16 + cl];
    accum(u0);
    accum(u1);
  }
  for (; e < d; e += 4) {
    int s = csr_src[start + e];
    accum(h16[(size_t)s * 16 + cl]);
  }

#pragma unroll
  for (int j = 0; j < 8; ++j) {
    acc[j] += __shfl_xor(acc[j], 16);
    acc[j] += __shfl_xor(acc[j], 32);
  }

  float inv = 1.0f / fmaxf((float)d, 1.0f);
  if (qe < 2) {
    unsigned short hs[4], ls[4];
    int b = qe * 4;
#pragma unroll
    for (int j = 0; j < 4; ++j) split_bf16(acc[b + j] * inv, hs[j], ls[j]);
    size_t o = (size_t)node * H + cl * 8 + qe * 4;
    *(uint2*)(a_hi + o) = make_uint2((unsigned)hs[0] | ((unsigned)hs[1] << 16),
                                     (unsigned)hs[2] | ((unsigned)hs[3] << 16));
    *(uint2*)(a_lo + o) = make_uint2((unsigned)ls[0] | ((unsigned)ls[1] << 16),
                                     (unsigned)ls[2] | ((unsigned)ls[3] << 16));
  }
}

// ---------------- weights-stationary barrier-free dual-GEMM (v2: no spill) ----------------
// All 4 W planes (128 KiB) in LDS, loaded once; 512 threads, 1 block/CU.
// Each wave streams 16-row tiles from an atomic counter. Per tile only ONE
// side's 8 A-frags (32 VGPRs) is in flight at a time: compute side0 from B0,
// prefetch next tile's side0 into B0, compute side1 from B1, prefetch side1.
// All code inlined via macros (no array-reference lambdas -> registers, not
// scratch). Live set ~140 VGPR. No __syncthreads in the main loop.

#define LOAD_SIDE(B, HIPL, LOPL, T)                                     \
  {                                                                     \
    int rr_ = (T) * 16 + m;                                             \
    if (rr_ >= N) rr_ = N - 1;                                          \
    const v8s* ph_ = (const v8s*)(HIPL + (size_t)rr_ * H) + q;          \
    const v8s* pl_ = (const v8s*)(LOPL + (size_t)rr_ * H) + q;          \
    _Pragma("unroll") for (int kb_ = 0; kb_ < 4; ++kb_) {               \
      B[kb_] = ph_[kb_ * 4];                                            \
      B[4 + kb_] = pl_[kb_ * 4];                                        \
    }                                                                   \
  }

#define COMPUTE_SIDE(B, S)                                              \
  {                                                                     \
    _Pragma("unroll") for (int kb_ = 0; kb_ < 4; ++kb_) {               \
      _Pragma("unroll") for (int c_ = 0; c_ < 8; ++c_) {                \
        v8s bh_ = WF[(S) * 4096 + c_ * 256 + kb_ * 64 + lane];          \
        v8s bl_ = WF[(S) * 4096 + 2048 + c_ * 256 + kb_ * 64 + lane];   \
        acc[c_] = __builtin_amdgcn_mfma_f32_16x16x32_bf16(B[kb_], bh_, acc[c_], 0, 0, 0);     \
        acc[c_] = __builtin_amdgcn_mfma_f32_16x16x32_bf16(B[4 + kb_], bh_, acc[c_], 0, 0, 0); \
        acc[c_] = __builtin_amdgcn_mfma_f32_16x16x32_bf16(B[kb_], bl_, acc[c_], 0, 0, 0);     \
      }                                                                 \
    }                                                                   \
  }

#define STORE_TILE(T)                                                   \
  {                                                                     \
    _Pragma("unroll") for (int c_ = 0; c_ < 8; ++c_) {                  \
      _Pragma("unroll") for (int i_ = 0; i_ < 4; ++i_) {                \
        int r_ = (T) * 16 + q * 4 + i_;                                 \
        if (r_ < N) {                                                   \
          float v_ = acc[c_][i_] + bv[c_];                              \
          if (RELU) v_ = fmaxf(v_, 0.f);                                \
          size_t o_ = (size_t)r_ * H + c_ * 16 + m;                     \
          if (FINAL) {                                                  \
            outf[o_] = v_;                                              \
          } else {                                                      \
            unsigned short hi_, lo_;                                    \
            split_bf16(v_, hi_, lo_);                                   \
            out_hi[o_] = hi_;                                           \
            out_lo[o_] = lo_;                                           \
          }                                                             \
        }                                                               \
      }                                                                 \
    }                                                                   \
    _Pragma("unroll") for (int c_ = 0; c_ < 8; ++c_)                    \
        acc[c_] = (v4f){0.f, 0.f, 0.f, 0.f};                            \
  }

template <int RELU, int FINAL>
__global__ __launch_bounds__(512, 1) void gemm_ws(
    const unsigned short* ag_hi, const unsigned short* ag_lo,
    const unsigned short* h_hi, const unsigned short* h_lo,
    const unsigned short* __restrict__ Wfrag, const float* __restrict__ bias,
    unsigned short* out_hi, unsigned short* out_lo, float* __restrict__ outf,
    int* __restrict__ tcnt, int N) {
  extern __shared__ unsigned short Wsh[];  // 65536 shorts = 128 KiB
  int tid = threadIdx.x;
  {  // cooperative W load: 8192 x 16 B
    const v8s* gs = (const v8s*)Wfrag;
    v8s* ls = (v8s*)Wsh;
#pragma unroll
    for (int i = 0; i < 16; ++i) ls[tid + i * 512] = gs[tid + i * 512];
  }
  int lane = tid & 63;
  int m = lane & 15, q = lane >> 4;
  float bv[8];
#pragma unroll
  for (int c = 0; c < 8; ++c) bv[c] = bias[c * 16 + m];
  __syncthreads();  // the only barrier

  const v8s* WF = (const v8s*)Wsh;
  int nT = (N + 15) >> 4;

  v8s B0[8];  // side 0 (aggr) frags: hi kb0..3, lo kb0..3
  v8s B1[8];  // side 1 (h)    frags
  v4f acc[8];
#pragma unroll
  for (int c = 0; c < 8; ++c) acc[c] = (v4f){0.f, 0.f, 0.f, 0.f};

  int tc = 0;
  if (lane == 0) tc = atomicAdd(tcnt, 1);
  tc = __shfl(tc, 0);
  if (tc >= nT) return;
  LOAD_SIDE(B0, ag_hi, ag_lo, tc);
  LOAD_SIDE(B1, h_hi, h_lo, tc);

  while (true) {
    COMPUTE_SIDE(B0, 0);
    int tn = 0;
    if (lane == 0) tn = atomicAdd(tcnt, 1);
    tn = __shfl(tn, 0);
    if (tn < nT) LOAD_SIDE(B0, ag_hi, ag_lo, tn);  // prefetch next side0
    COMPUTE_SIDE(B1, 1);
    if (tn < nT) LOAD_SIDE(B1, h_hi, h_lo, tn);    // prefetch next side1
    STORE_TILE(tc);                                // also resets acc
    if (tn >= nT) return;
    tc = tn;
  }
}

// ---------------- launch ----------------

extern "C" void kernel_launch(void* const* d_in, const int* in_sizes, int n_in,
                              void* d_out, int out_size, void* d_ws, size_t ws_size,
                              hipStream_t stream) {
  const int* node_id = (const int*)d_in[0];
  const int* edge_index = (const int*)d_in[1];
  const float* emb = (const float*)d_in[2];
  const float* W1l = (const float*)d_in[3];
  const float* b1l = (const float*)d_in[4];
  const float* W1r = (const float*)d_in[5];
  const float* W2l = (const float*)d_in[6];
  const float* b2l = (const float*)d_in[7];
  const float* W2r = (const float*)d_in[8];
  const float* W3l = (const float*)d_in[9];
  const float* b3l = (const float*)d_in[10];
  const float* W3r = (const float*)d_in[11];

  int N = in_sizes[0];
  int E = in_sizes[1] / 2;
  const int* src = edge_index;
  const int* dst = edge_index + E;

  char* w = (char*)d_ws;
  auto alloc = [&](size_t bytes) {
    void* p = (void*)w;
    w += (bytes + 255) & ~(size_t)255;
    return p;
  };
  int* deg = (int*)alloc((size_t)N * 4);
  int* cursor = (int*)alloc((size_t)N * 4);
  int* row_start = (int*)alloc((size_t)N * 4);
  int* incl = (int*)alloc((size_t)N * 4);
  int* blk_sum = (int*)alloc(1024);
  int* blk_off = (int*)alloc(1024);
  int* csr_src = (int*)alloc((size_t)E * 4);
  int* tcnt = (int*)alloc(256);  // 3 work-steal counters
  unsigned short* P0h = (unsigned short*)alloc((size_t)N * H * 2);
  unsigned short* P0l = (unsigned short*)alloc((size_t)N * H * 2);
  unsigned short* P1h = (unsigned short*)alloc((size_t)N * H * 2);
  unsigned short* P1l = (unsigned short*)alloc((size_t)N * H * 2);
  unsigned short* Wf = (unsigned short*)alloc((size_t)3 * 65536 * 2);

  static int attr_done = 0;
  if (!attr_done) {
    hipFuncSetAttribute(reinterpret_cast<const void*>(&gemm_ws<1, 0>),
                        hipFuncAttributeMaxDynamicSharedMemorySize, 131072);
    hipFuncSetAttribute(reinterpret_cast<const void*>(&gemm_ws<0, 1>),
                        hipFuncAttributeMaxDynamicSharedMemorySize, 131072);
    attr_done = 1;
  }

  hipMemsetAsync(deg, 0, (size_t)N * 4, stream);
  hipMemsetAsync(cursor, 0, (size_t)N * 4, stream);
  hipMemsetAsync(tcnt, 0, 256, stream);

  hist_kernel<<<(E + 255) / 256, 256, 0, stream>>>(dst, deg, E);
  int SB = (N + 1023) / 1024;
  scan1_kernel<<<SB, 1024, 0, stream>>>(deg, incl, blk_sum, N);
  scan2_kernel<<<1, 256, 0, stream>>>(blk_sum, blk_off, SB);
  rowstart_kernel<<<(N + 255) / 256, 256, 0, stream>>>(incl, deg, blk_off, row_start, N);
  fill_kernel<<<(E + 255) / 256, 256, 0, stream>>>(src, dst, row_start, cursor, csr_src, E);

  gather_kernel<<<(N * 32 + 255) / 256, 256, 0, stream>>>(emb, node_id, P0h, P0l, N);
  wsplit_kernel<<<384, 256, 0, stream>>>(W1l, W1r, W2l, W2r, W3l, W3r, Wf);

  int gag = (N + 3) / 4;

  // layer 1: h1 = P0; aggr1 -> P1; gemm writes in-place over P1 => h2 = P1
  aggregate_kernel<<<gag, 256, 0, stream>>>(P0h, csr_src, row_start, deg, P1h, P1l, N);
  gemm_ws<1, 0><<<256, 512, 131072, stream>>>(P1h, P1l, P0h, P0l, Wf, b1l,
                                              P1h, P1l, nullptr, tcnt, N);

  // layer 2: aggr2 -> P0 (over dead h1); gemm in-place over P0 => h3 = P0
  aggregate_kernel<<<gag, 256, 0, stream>>>(P1h, csr_src, row_start, deg, P0h, P0l, N);
  gemm_ws<1, 0><<<256, 512, 131072, stream>>>(P0h, P0l, P1h, P1l, Wf + 65536, b2l,
                                              P0h, P0l, nullptr, tcnt + 1, N);

  // layer 3: aggr3 -> P1 (over dead h2); final gemm -> fp32 d_out
  aggregate_kernel<<<gag, 256, 0, stream>>>(P0h, csr_src, row_start, deg, P1h, P1l, N);
  gemm_ws<0, 1><<<256, 512, 131072, stream>>>(P1h, P1l, P0h, P0l, Wf + 131072, b3l,
                                              nullptr, nullptr, (float*)d_out, tcnt + 2, N);
}

// Round 3
// 1043.124 us; speedup vs baseline: 1.1303x; 1.1303x over previous
//
#include <hip/hip_runtime.h>

#define H 128

typedef float v4f __attribute__((ext_vector_type(4)));
typedef short v8s __attribute__((ext_vector_type(8)));

// ---------------- bf16 helpers ----------------

__device__ inline unsigned short bf16_rne(float x) {
  unsigned u = __builtin_bit_cast(unsigned, x);
  unsigned r = u + 0x7FFF + ((u >> 16) & 1);
  return (unsigned short)(r >> 16);
}

__device__ inline void split_bf16(float x, unsigned short& hi, unsigned short& lo) {
  unsigned u = __builtin_bit_cast(unsigned, x);
  unsigned r = u + 0x7FFF + ((u >> 16) & 1);  // RNE round to bf16
  hi = (unsigned short)(r >> 16);
  float hf = __builtin_bit_cast(float, r & 0xFFFF0000u);
  float d = x - hf;
  unsigned ud = __builtin_bit_cast(unsigned, d);
  unsigned rd = ud + 0x7FFF + ((ud >> 16) & 1);
  lo = (unsigned short)(rd >> 16);
}

// ---------------- CSR build (unchanged) ----------------

__global__ void hist_kernel(const int* __restrict__ dst, int* __restrict__ deg, int E) {
  int e = blockIdx.x * 256 + threadIdx.x;
  if (e < E) atomicAdd(&deg[dst[e]], 1);
}

__global__ __launch_bounds__(1024) void scan1_kernel(const int* __restrict__ deg,
                                                     int* __restrict__ incl,
                                                     int* __restrict__ blk_sum, int N) {
  __shared__ int lds[1024];
  int t = threadIdx.x;
  int i = blockIdx.x * 1024 + t;
  int v = (i < N) ? deg[i] : 0;
  lds[t] = v;
  __syncthreads();
  for (int off = 1; off < 1024; off <<= 1) {
    int x = (t >= off) ? lds[t - off] : 0;
    __syncthreads();
    lds[t] += x;
    __syncthreads();
  }
  if (i < N) incl[i] = lds[t];
  if (t == 1023) blk_sum[blockIdx.x] = lds[1023];
}

__global__ void scan2_kernel(const int* __restrict__ blk_sum, int* __restrict__ blk_off, int B) {
  __shared__ int lds[256];
  int t = threadIdx.x;
  int v = (t < B) ? blk_sum[t] : 0;
  lds[t] = v;
  __syncthreads();
  for (int off = 1; off < 256; off <<= 1) {
    int x = (t >= off) ? lds[t - off] : 0;
    __syncthreads();
    lds[t] += x;
    __syncthreads();
  }
  blk_off[t] = lds[t] - v;  // exclusive scan of block sums
}

__global__ void rowstart_kernel(const int* __restrict__ incl, const int* __restrict__ deg,
                                const int* __restrict__ blk_off, int* __restrict__ row_start,
                                int N) {
  int i = blockIdx.x * 256 + threadIdx.x;
  if (i < N) row_start[i] = blk_off[i >> 10] + incl[i] - deg[i];
}

__global__ void fill_kernel(const int* __restrict__ src, const int* __restrict__ dst,
                            const int* __restrict__ row_start, int* __restrict__ cursor,
                            int* __restrict__ csr_src, int E) {
  int e = blockIdx.x * 256 + threadIdx.x;
  if (e < E) {
    int d = dst[e];
    int p = atomicAdd(&cursor[d], 1);
    csr_src[row_start[d] + p] = src[e];
  }
}

// ---------------- feature gather: emb -> bf16 hi/lo planes ----------------

__global__ void gather_kernel(const float* __restrict__ emb, const int* __restrict__ node_id,
                              unsigned short* __restrict__ h_hi, unsigned short* __restrict__ h_lo,
                              int N) {
  int i = blockIdx.x * 256 + threadIdx.x;
  if (i < N * 32) {
    int n = i >> 5, g = i & 31;
    float4 v = ((const float4*)emb)[(size_t)node_id[n] * 32 + g];
    float vv[4] = {v.x, v.y, v.z, v.w};
    unsigned short hs[4], ls[4];
#pragma unroll
    for (int k = 0; k < 4; ++k) split_bf16(vv[k], hs[k], ls[k]);
    size_t base = (size_t)n * H + g * 4;
    *(uint2*)(h_hi + base) = make_uint2((unsigned)hs[0] | ((unsigned)hs[1] << 16),
                                        (unsigned)hs[2] | ((unsigned)hs[3] << 16));
    *(uint2*)(h_lo + base) = make_uint2((unsigned)ls[0] | ((unsigned)ls[1] << 16),
                                        (unsigned)ls[2] | ((unsigned)ls[3] << 16));
  }
}

// ---------------- weight pre-split into MFMA-frag-ordered planes ----------------
// Frag order per plane (16384 shorts): e = c*2048 + kb*512 + q*128 + m*8 + j
// holds W[col = c*16+m][k = kb*32 + q*8 + j]. Buffer layout:
// Wf[layer][side l/r][hi,lo][16384], layer stride 65536 shorts.

__global__ void wsplit_kernel(const float* __restrict__ W0, const float* __restrict__ W1,
                              const float* __restrict__ W2, const float* __restrict__ W3,
                              const float* __restrict__ W4, const float* __restrict__ W5,
                              unsigned short* __restrict__ Wf) {
  int idx = blockIdx.x * 256 + threadIdx.x;  // 0..98303 (6 planes x 16384)
  int sp = idx >> 14;                        // {W1l,W1r,W2l,W2r,W3l,W3r}
  int e = idx & 16383;
  const float* src = sp == 0 ? W0 : sp == 1 ? W1 : sp == 2 ? W2
                   : sp == 3 ? W3 : sp == 4 ? W4 : W5;
  int c = e >> 11;
  int kb = (e >> 9) & 3;
  int qq = (e >> 7) & 3;
  int mm = (e >> 3) & 15;
  int j = e & 7;
  int col = c * 16 + mm;
  int k = kb * 32 + qq * 8 + j;
  unsigned short hi, lo;
  split_bf16(src[col * H + k], hi, lo);
  size_t base = (size_t)(sp >> 1) * 65536 + (size_t)(sp & 1) * 32768 + e;
  Wf[base] = hi;          // hi plane
  Wf[base + 16384] = lo;  // lo plane
}

// ---------------- mean aggregation (CSR, bf16 gather, split-plane output) ----------------

__global__ __launch_bounds__(256) void aggregate_kernel(const unsigned short* __restrict__ hb,
                                                        const int* __restrict__ csr_src,
                                                        const int* __restrict__ row_start,
                                                        const int* __restrict__ deg,
                                                        unsigned short* __restrict__ a_hi,
                                                        unsigned short* __restrict__ a_lo, int N) {
  int node = blockIdx.x * 4 + (threadIdx.x >> 6);
  if (node >= N) return;
  int lane = threadIdx.x & 63;
  int qe = lane >> 4;  // edge slot 0..3
  int cl = lane & 15;  // channel group: channels cl*8 .. cl*8+7
  const uint4* __restrict__ h16 = (const uint4*)hb;

  int start = row_start[node];
  int d = deg[node];

  float acc[8] = {0.f, 0.f, 0.f, 0.f, 0.f, 0.f, 0.f, 0.f};

  auto accum = [&](uint4 u) {
    unsigned uu[4] = {u.x, u.y, u.z, u.w};
#pragma unroll
    for (int j = 0; j < 4; ++j) {
      acc[2 * j] += __builtin_bit_cast(float, uu[j] << 16);
      acc[2 * j + 1] += __builtin_bit_cast(float, uu[j] & 0xFFFF0000u);
    }
  };

  int e = qe;
  for (; e + 4 < d; e += 8) {
    int s0 = csr_src[start + e];
    int s1 = csr_src[start + e + 4];
    uint4 u0 = h16[(size_t)s0 * 16 + cl];
    uint4 u1 = h16[(size_t)s1 * 16 + cl];
    accum(u0);
    accum(u1);
  }
  for (; e < d; e += 4) {
    int s = csr_src[start + e];
    accum(h16[(size_t)s * 16 + cl]);
  }

#pragma unroll
  for (int j = 0; j < 8; ++j) {
    acc[j] += __shfl_xor(acc[j], 16);
    acc[j] += __shfl_xor(acc[j], 32);
  }

  float inv = 1.0f / fmaxf((float)d, 1.0f);
  if (qe < 2) {
    unsigned short hs[4], ls[4];
    int b = qe * 4;
#pragma unroll
    for (int j = 0; j < 4; ++j) split_bf16(acc[b + j] * inv, hs[j], ls[j]);
    size_t o = (size_t)node * H + cl * 8 + qe * 4;
    *(uint2*)(a_hi + o) = make_uint2((unsigned)hs[0] | ((unsigned)hs[1] << 16),
                                     (unsigned)hs[2] | ((unsigned)hs[3] << 16));
    *(uint2*)(a_lo + o) = make_uint2((unsigned)ls[0] | ((unsigned)ls[1] << 16),
                                     (unsigned)ls[2] | ((unsigned)ls[3] << 16));
  }
}

// ---------------- weights-stationary barrier-free dual-GEMM (v3) ----------------
// All 4 W planes (128 KiB) in LDS, loaded once; 512 threads (8 waves),
// 1 block/CU, grid = 256. Static wave->tile map (stride 2048), no atomics,
// no prefetch double-buffers: per 16-row tile a wave issues all 16 A-frag
// loads (a[8], b[8], statically indexed, loop-local), runs 2x96 MFMAs off
// LDS-resident W frags, stores, moves on. Live set ~105 VGPR -> no spill.
// Latency hiding via 8 waves/CU TLP. GEMM is row-local so output may alias
// the aggr input planes (in-place).

template <int RELU, int FINAL>
__global__ __launch_bounds__(512) void gemm_ws(
    const unsigned short* ag_hi, const unsigned short* ag_lo,
    const unsigned short* h_hi, const unsigned short* h_lo,
    const unsigned short* __restrict__ Wfrag, const float* __restrict__ bias,
    unsigned short* out_hi, unsigned short* out_lo, float* __restrict__ outf,
    int N) {
  extern __shared__ unsigned short Wsh[];  // 65536 shorts = 128 KiB
  int tid = threadIdx.x;
  {  // cooperative W load: 8192 x 16 B
    const v8s* gs = (const v8s*)Wfrag;
    v8s* ls = (v8s*)Wsh;
#pragma unroll
    for (int i = 0; i < 16; ++i) ls[tid + i * 512] = gs[tid + i * 512];
  }
  int lane = tid & 63;
  int m = lane & 15, q = lane >> 4;
  float bv[8];
#pragma unroll
  for (int c = 0; c < 8; ++c) bv[c] = bias[c * 16 + m];
  __syncthreads();  // the only barrier

  const v8s* WF = (const v8s*)Wsh;
  int nT = (N + 15) >> 4;
  int wid = blockIdx.x * 8 + (tid >> 6);
  int stride = gridDim.x * 8;

#pragma unroll 1
  for (int t = wid; t < nT; t += stride) {
    int rr = t * 16 + m;
    if (rr >= N) rr = N - 1;
    const v8s* pah = (const v8s*)(ag_hi + (size_t)rr * H) + q;
    const v8s* pal = (const v8s*)(ag_lo + (size_t)rr * H) + q;
    const v8s* pbh = (const v8s*)(h_hi + (size_t)rr * H) + q;
    const v8s* pbl = (const v8s*)(h_lo + (size_t)rr * H) + q;

    v8s a[8], b[8];  // a: side0 (aggr) hi kb0..3, lo kb0..3; b: side1 (h)
#pragma unroll
    for (int kb = 0; kb < 4; ++kb) {
      a[kb] = pah[kb * 4];
      a[4 + kb] = pal[kb * 4];
      b[kb] = pbh[kb * 4];
      b[4 + kb] = pbl[kb * 4];
    }

    v4f acc[8];
#pragma unroll
    for (int c = 0; c < 8; ++c) acc[c] = (v4f){0.f, 0.f, 0.f, 0.f};

    // side 0: aggr @ Wl
#pragma unroll
    for (int kb = 0; kb < 4; ++kb) {
#pragma unroll
      for (int c = 0; c < 8; ++c) {
        v8s bh = WF[c * 256 + kb * 64 + lane];
        v8s bl = WF[2048 + c * 256 + kb * 64 + lane];
        acc[c] = __builtin_amdgcn_mfma_f32_16x16x32_bf16(a[kb], bh, acc[c], 0, 0, 0);
        acc[c] = __builtin_amdgcn_mfma_f32_16x16x32_bf16(a[4 + kb], bh, acc[c], 0, 0, 0);
        acc[c] = __builtin_amdgcn_mfma_f32_16x16x32_bf16(a[kb], bl, acc[c], 0, 0, 0);
      }
    }
    // side 1: h @ Wr
#pragma unroll
    for (int kb = 0; kb < 4; ++kb) {
#pragma unroll
      for (int c = 0; c < 8; ++c) {
        v8s bh = WF[4096 + c * 256 + kb * 64 + lane];
        v8s bl = WF[4096 + 2048 + c * 256 + kb * 64 + lane];
        acc[c] = __builtin_amdgcn_mfma_f32_16x16x32_bf16(b[kb], bh, acc[c], 0, 0, 0);
        acc[c] = __builtin_amdgcn_mfma_f32_16x16x32_bf16(b[4 + kb], bh, acc[c], 0, 0, 0);
        acc[c] = __builtin_amdgcn_mfma_f32_16x16x32_bf16(b[kb], bl, acc[c], 0, 0, 0);
      }
    }

    // epilogue
#pragma unroll
    for (int c = 0; c < 8; ++c) {
#pragma unroll
      for (int i = 0; i < 4; ++i) {
        int r = t * 16 + q * 4 + i;
        if (r < N) {
          float v = acc[c][i] + bv[c];
          if (RELU) v = fmaxf(v, 0.f);
          size_t o = (size_t)r * H + c * 16 + m;
          if (FINAL) {
            outf[o] = v;
          } else {
            unsigned short hi, lo;
            split_bf16(v, hi, lo);
            out_hi[o] = hi;
            out_lo[o] = lo;
          }
        }
      }
    }
  }
}

// ---------------- launch ----------------

extern "C" void kernel_launch(void* const* d_in, const int* in_sizes, int n_in,
                              void* d_out, int out_size, void* d_ws, size_t ws_size,
                              hipStream_t stream) {
  const int* node_id = (const int*)d_in[0];
  const int* edge_index = (const int*)d_in[1];
  const float* emb = (const float*)d_in[2];
  const float* W1l = (const float*)d_in[3];
  const float* b1l = (const float*)d_in[4];
  const float* W1r = (const float*)d_in[5];
  const float* W2l = (const float*)d_in[6];
  const float* b2l = (const float*)d_in[7];
  const float* W2r = (const float*)d_in[8];
  const float* W3l = (const float*)d_in[9];
  const float* b3l = (const float*)d_in[10];
  const float* W3r = (const float*)d_in[11];

  int N = in_sizes[0];
  int E = in_sizes[1] / 2;
  const int* src = edge_index;
  const int* dst = edge_index + E;

  char* w = (char*)d_ws;
  auto alloc = [&](size_t bytes) {
    void* p = (void*)w;
    w += (bytes + 255) & ~(size_t)255;
    return p;
  };
  int* deg = (int*)alloc((size_t)N * 4);
  int* cursor = (int*)alloc((size_t)N * 4);
  int* row_start = (int*)alloc((size_t)N * 4);
  int* incl = (int*)alloc((size_t)N * 4);
  int* blk_sum = (int*)alloc(1024);
  int* blk_off = (int*)alloc(1024);
  int* csr_src = (int*)alloc((size_t)E * 4);
  unsigned short* P0h = (unsigned short*)alloc((size_t)N * H * 2);
  unsigned short* P0l = (unsigned short*)alloc((size_t)N * H * 2);
  unsigned short* P1h = (unsigned short*)alloc((size_t)N * H * 2);
  unsigned short* P1l = (unsigned short*)alloc((size_t)N * H * 2);
  unsigned short* Wf = (unsigned short*)alloc((size_t)3 * 65536 * 2);

  static int attr_done = 0;
  if (!attr_done) {
    hipFuncSetAttribute(reinterpret_cast<const void*>(&gemm_ws<1, 0>),
                        hipFuncAttributeMaxDynamicSharedMemorySize, 131072);
    hipFuncSetAttribute(reinterpret_cast<const void*>(&gemm_ws<0, 1>),
                        hipFuncAttributeMaxDynamicSharedMemorySize, 131072);
    attr_done = 1;
  }

  hipMemsetAsync(deg, 0, (size_t)N * 4, stream);
  hipMemsetAsync(cursor, 0, (size_t)N * 4, stream);

  hist_kernel<<<(E + 255) / 256, 256, 0, stream>>>(dst, deg, E);
  int SB = (N + 1023) / 1024;
  scan1_kernel<<<SB, 1024, 0, stream>>>(deg, incl, blk_sum, N);
  scan2_kernel<<<1, 256, 0, stream>>>(blk_sum, blk_off, SB);
  rowstart_kernel<<<(N + 255) / 256, 256, 0, stream>>>(incl, deg, blk_off, row_start, N);
  fill_kernel<<<(E + 255) / 256, 256, 0, stream>>>(src, dst, row_start, cursor, csr_src, E);

  gather_kernel<<<(N * 32 + 255) / 256, 256, 0, stream>>>(emb, node_id, P0h, P0l, N);
  wsplit_kernel<<<384, 256, 0, stream>>>(W1l, W1r, W2l, W2r, W3l, W3r, Wf);

  int gag = (N + 3) / 4;

  // layer 1: h1 = P0; aggr1 -> P1; gemm writes in-place over P1 => h2 = P1
  aggregate_kernel<<<gag, 256, 0, stream>>>(P0h, csr_src, row_start, deg, P1h, P1l, N);
  gemm_ws<1, 0><<<256, 512, 131072, stream>>>(P1h, P1l, P0h, P0l, Wf, b1l,
                                              P1h, P1l, nullptr, N);

  // layer 2: aggr2 -> P0 (over dead h1); gemm in-place over P0 => h3 = P0
  aggregate_kernel<<<gag, 256, 0, stream>>>(P1h, csr_src, row_start, deg, P0h, P0l, N);
  gemm_ws<1, 0><<<256, 512, 131072, stream>>>(P0h, P0l, P1h, P1l, Wf + 65536, b2l,
                                              P0h, P0l, nullptr, N);

  // layer 3: aggr3 -> P1 (over dead h2); final gemm -> fp32 d_out
  aggregate_kernel<<<gag, 256, 0, stream>>>(P0h, csr_src, row_start, deg, P1h, P1l, N);
  gemm_ws<0, 1><<<256, 512, 131072, stream>>>(P1h, P1l, P0h, P0l, Wf + 131072, b3l,
                                              nullptr, nullptr, (float*)d_out, N);
}

// Round 5
// 493.303 us; speedup vs baseline: 2.3901x; 2.1146x over previous
//
#include <hip/hip_runtime.h>

#define H 128

typedef float v4f __attribute__((ext_vector_type(4)));
typedef short v8s __attribute__((ext_vector_type(8)));

// ---------------- bf16 helpers ----------------

__device__ inline unsigned short bf16_rne(float x) {
  unsigned u = __builtin_bit_cast(unsigned, x);
  unsigned r = u + 0x7FFF + ((u >> 16) & 1);
  return (unsigned short)(r >> 16);
}

__device__ inline void split_bf16(float x, unsigned short& hi, unsigned short& lo) {
  unsigned u = __builtin_bit_cast(unsigned, x);
  unsigned r = u + 0x7FFF + ((u >> 16) & 1);  // RNE round to bf16
  hi = (unsigned short)(r >> 16);
  float hf = __builtin_bit_cast(float, r & 0xFFFF0000u);
  float d = x - hf;
  unsigned ud = __builtin_bit_cast(unsigned, d);
  unsigned rd = ud + 0x7FFF + ((ud >> 16) & 1);
  lo = (unsigned short)(rd >> 16);
}

// ---------------- CSR build ----------------

__global__ void hist_kernel(const int* __restrict__ dst, int* __restrict__ deg, int E) {
  int e = blockIdx.x * 256 + threadIdx.x;
  if (e < E) atomicAdd(&deg[dst[e]], 1);
}

__global__ __launch_bounds__(1024) void scan1_kernel(const int* __restrict__ deg,
                                                     int* __restrict__ incl,
                                                     int* __restrict__ blk_sum, int N) {
  __shared__ int lds[1024];
  int t = threadIdx.x;
  int i = blockIdx.x * 1024 + t;
  int v = (i < N) ? deg[i] : 0;
  lds[t] = v;
  __syncthreads();
  for (int off = 1; off < 1024; off <<= 1) {
    int x = (t >= off) ? lds[t - off] : 0;
    __syncthreads();
    lds[t] += x;
    __syncthreads();
  }
  if (i < N) incl[i] = lds[t];
  if (t == 1023) blk_sum[blockIdx.x] = lds[1023];
}

__global__ void scan2_kernel(const int* __restrict__ blk_sum, int* __restrict__ blk_off, int B) {
  __shared__ int lds[256];
  int t = threadIdx.x;
  int v = (t < B) ? blk_sum[t] : 0;
  lds[t] = v;
  __syncthreads();
  for (int off = 1; off < 256; off <<= 1) {
    int x = (t >= off) ? lds[t - off] : 0;
    __syncthreads();
    lds[t] += x;
    __syncthreads();
  }
  blk_off[t] = lds[t] - v;  // exclusive scan of block sums
}

__global__ void rowstart_kernel(const int* __restrict__ incl, const int* __restrict__ deg,
                                const int* __restrict__ blk_off, int* __restrict__ row_start,
                                int N) {
  int i = blockIdx.x * 256 + threadIdx.x;
  if (i < N) row_start[i] = blk_off[i >> 10] + incl[i] - deg[i];
}

__global__ void fill_kernel(const int* __restrict__ src, const int* __restrict__ dst,
                            const int* __restrict__ row_start, int* __restrict__ cursor,
                            int* __restrict__ csr_src, int E) {
  int e = blockIdx.x * 256 + threadIdx.x;
  if (e < E) {
    int d = dst[e];
    int p = atomicAdd(&cursor[d], 1);
    csr_src[row_start[d] + p] = src[e];
  }
}

// ---------------- feature gather (fp32 + bf16 image) — r0 verbatim ----------------

__global__ void gather_kernel(const float* __restrict__ emb, const int* __restrict__ node_id,
                              float* __restrict__ h, unsigned short* __restrict__ hb, int N) {
  int i = blockIdx.x * 256 + threadIdx.x;
  if (i < N * 32) {
    int n = i >> 5, q = i & 31;
    float4 v = ((const float4*)emb)[(size_t)node_id[n] * 32 + q];
    ((float4*)h)[(size_t)n * 32 + q] = v;
    unsigned b0 = bf16_rne(v.x), b1 = bf16_rne(v.y), b2 = bf16_rne(v.z), b3 = bf16_rne(v.w);
    *(uint2*)(hb + (size_t)n * H + q * 4) = make_uint2(b0 | (b1 << 16), b2 | (b3 << 16));
  }
}

// ---------------- weight pre-split: 6x [128x128] fp32 -> bf16 hi/lo planes ----------------

__global__ void wsplit_kernel(const float* __restrict__ W0, const float* __restrict__ W1,
                              const float* __restrict__ W2, const float* __restrict__ W3,
                              const float* __restrict__ W4, const float* __restrict__ W5,
                              unsigned short* __restrict__ hi, unsigned short* __restrict__ lo) {
  int i = blockIdx.x * 256 + threadIdx.x;  // 0..24575 (6 planes x 4096 float4-groups)
  int plane = i >> 12;
  int e = (i & 4095) * 4;
  const float* src = plane == 0 ? W0 : plane == 1 ? W1 : plane == 2 ? W2
                   : plane == 3 ? W3 : plane == 4 ? W4 : W5;
  float4 v = *(const float4*)(src + e);
  float vv[4] = {v.x, v.y, v.z, v.w};
  unsigned short hs[4], ls[4];
#pragma unroll
  for (int k = 0; k < 4; ++k) split_bf16(vv[k], hs[k], ls[k]);
  size_t base = (size_t)plane * 16384 + e;
  *(uint2*)(&hi[base]) = make_uint2((unsigned)hs[0] | ((unsigned)hs[1] << 16),
                                    (unsigned)hs[2] | ((unsigned)hs[3] << 16));
  *(uint2*)(&lo[base]) = make_uint2((unsigned)ls[0] | ((unsigned)ls[1] << 16),
                                    (unsigned)ls[2] | ((unsigned)ls[3] << 16));
}

// ---------------- mean aggregation (CSR, bf16 gather, split-plane output) ----------------
// One 64-lane wave per node; fp32 accumulate; output as pre-split bf16 hi/lo
// planes (hi = bf16_rne(mean), lo = bf16_rne(mean - hi)) so the GEMM's
// aggr-side staging is a pure copy. Producer pattern proven in rounds 1-3.

__global__ __launch_bounds__(256) void aggregate_kernel(const unsigned short* __restrict__ hb,
                                                        const int* __restrict__ csr_src,
                                                        const int* __restrict__ row_start,
                                                        const int* __restrict__ deg,
                                                        unsigned short* __restrict__ a_hi,
                                                        unsigned short* __restrict__ a_lo, int N) {
  int node = blockIdx.x * 4 + (threadIdx.x >> 6);
  if (node >= N) return;
  int lane = threadIdx.x & 63;
  int qe = lane >> 4;  // edge slot 0..3
  int cl = lane & 15;  // channel group: channels cl*8 .. cl*8+7
  const uint4* __restrict__ h16 = (const uint4*)hb;

  int start = row_start[node];
  int d = deg[node];

  float acc[8] = {0.f, 0.f, 0.f, 0.f, 0.f, 0.f, 0.f, 0.f};

  auto accum = [&](uint4 u) {
    unsigned uu[4] = {u.x, u.y, u.z, u.w};
#pragma unroll
    for (int j = 0; j < 4; ++j) {
      acc[2 * j] += __builtin_bit_cast(float, uu[j] << 16);
      acc[2 * j + 1] += __builtin_bit_cast(float, uu[j] & 0xFFFF0000u);
    }
  };

  int e = qe;
  for (; e + 4 < d; e += 8) {
    int s0 = csr_src[start + e];
    int s1 = csr_src[start + e + 4];
    uint4 u0 = h16[(size_t)s0 * 16 + cl];
    uint4 u1 = h16[(size_t)s1 * 16 + cl];
    accum(u0);
    accum(u1);
  }
  for (; e < d; e += 4) {
    int s = csr_src[start + e];
    accum(h16[(size_t)s * 16 + cl]);
  }

#pragma unroll
  for (int j = 0; j < 8; ++j) {
    acc[j] += __shfl_xor(acc[j], 16);
    acc[j] += __shfl_xor(acc[j], 32);
  }

  float inv = 1.0f / fmaxf((float)d, 1.0f);
  if (qe < 2) {
    unsigned short hs[4], ls[4];
    int b = qe * 4;
#pragma unroll
    for (int j = 0; j < 4; ++j) split_bf16(acc[b + j] * inv, hs[j], ls[j]);
    size_t o = (size_t)node * H + cl * 8 + qe * 4;
    *(uint2*)(a_hi + o) = make_uint2((unsigned)hs[0] | ((unsigned)hs[1] << 16),
                                     (unsigned)hs[2] | ((unsigned)hs[3] << 16));
    *(uint2*)(a_lo + o) = make_uint2((unsigned)ls[0] | ((unsigned)ls[1] << 16),
                                     (unsigned)ls[2] | ((unsigned)ls[3] << 16));
  }
}

// ---------------- split-bf16 MFMA dual-GEMM (r0 engine; ag side pre-split) ----------------
// out = act(aggr@Wl^T + bl + h@Wr^T) via Xhi*Whi + Xlo*Whi + Xhi*Wlo per side.
// BM=128 rows/block, 4 waves x 32 rows, static 32 KiB LDS, barriered K-chunks
// (known-good codegen: VGPR~100, no scratch). Side 0 (aggr) staging is a pure
// uint2 copy from pre-split planes (no split_bf16 VALU); side 1 (h) keeps
// r0's fp32-load + split staging. Aliasing pattern identical to r0: reads
// hbuf (h), writes hbuf (out) + hb image; ag planes are never written here.

template <int RELU>
__global__ __launch_bounds__(256) void gemm_mfma(
    const unsigned short* __restrict__ ag_hi, const unsigned short* __restrict__ ag_lo,
    const float* h,
    const unsigned short* __restrict__ Wl_hi, const unsigned short* __restrict__ Wl_lo,
    const unsigned short* __restrict__ Wr_hi, const unsigned short* __restrict__ Wr_lo,
    const float* __restrict__ bias,
    float* out, unsigned short* hb_out, int N) {
  __shared__ __align__(16) unsigned short Ah[4096];  // 8 tiles x 512 shorts (frag-order)
  __shared__ __align__(16) unsigned short Al[4096];
  __shared__ __align__(16) unsigned short Wh[4096];
  __shared__ __align__(16) unsigned short Wl_[4096];

  int tid = threadIdx.x;
  int wave = tid >> 6, lane = tid & 63;
  int m = lane & 15, q = lane >> 4;
  int block_row = blockIdx.x * 128;

  v4f acc[16];  // [tr*8 + c], tr in {0,1}, c in 0..7
#pragma unroll
  for (int t = 0; t < 16; ++t) acc[t] = (v4f){0.f, 0.f, 0.f, 0.f};

  for (int side = 0; side < 2; ++side) {
    const unsigned short* WH = side ? Wr_hi : Wl_hi;
    const unsigned short* WL = side ? Wr_lo : Wl_lo;

    for (int kb = 0; kb < 4; ++kb) {
      __syncthreads();  // previous chunk's frag reads complete before overwrite

      if (side == 0) {
        // --- stage A chunk from pre-split aggr planes: pure copies ---
#pragma unroll
        for (int p = 0; p < 4; ++p) {
          int s = p * 256 + tid;  // 0..1023
          int row = s >> 3;       // 0..127
          int g = s & 7;          // uint2 group (4 channels) along k
          int grow = block_row + row;
          if (grow >= N) grow = N - 1;
          size_t gsrc = (size_t)grow * H + kb * 32 + g * 4;
          uint2 vh = *(const uint2*)(ag_hi + gsrc);
          uint2 vl = *(const uint2*)(ag_lo + gsrc);
          int off = (row >> 4) * 512 + (((g >> 1) * 16) + (row & 15)) * 8 + (g & 1) * 4;
          *(uint2*)(&Ah[off]) = vh;
          *(uint2*)(&Al[off]) = vl;
        }
      } else {
        // --- stage A chunk from fp32 h (r0 path: load + split) ---
#pragma unroll
        for (int p = 0; p < 4; ++p) {
          int s = p * 256 + tid;  // 0..1023
          int row = s >> 3;       // 0..127
          int g = s & 7;          // float4 group along k
          int grow = block_row + row;
          if (grow >= N) grow = N - 1;
          float4 v = *(const float4*)(h + (size_t)grow * H + kb * 32 + g * 4);
          float vv[4] = {v.x, v.y, v.z, v.w};
          unsigned short hs[4], ls[4];
#pragma unroll
          for (int k = 0; k < 4; ++k) split_bf16(vv[k], hs[k], ls[k]);
          int off = (row >> 4) * 512 + (((g >> 1) * 16) + (row & 15)) * 8 + (g & 1) * 4;
          *(uint2*)(&Ah[off]) = make_uint2((unsigned)hs[0] | ((unsigned)hs[1] << 16),
                                           (unsigned)hs[2] | ((unsigned)hs[3] << 16));
          *(uint2*)(&Al[off]) = make_uint2((unsigned)ls[0] | ((unsigned)ls[1] << 16),
                                           (unsigned)ls[2] | ((unsigned)ls[3] << 16));
        }
      }

      // --- stage W pair chunk (128 rows x 32 k bf16, frag-order) ---
#pragma unroll
      for (int p = 0; p < 2; ++p) {
        int s = p * 256 + tid;  // 0..511 (16B units)
        int row = s >> 2;       // 0..127 (W row = output col)
        int g2 = s & 3;         // k-group of 8
        size_t gsrc = (size_t)row * H + kb * 32 + g2 * 8;
        v8s wh = *(const v8s*)(WH + gsrc);
        v8s wl = *(const v8s*)(WL + gsrc);
        int off = (row >> 4) * 512 + (g2 * 16 + (row & 15)) * 8;
        *(v8s*)(&Wh[off]) = wh;
        *(v8s*)(&Wl_[off]) = wl;
      }

      __syncthreads();

      // --- compute: 3 split-combos x 2 row-tiles x 8 col-tiles ---
      const v8s* AhF = (const v8s*)Ah;
      const v8s* AlF = (const v8s*)Al;
      const v8s* WhF = (const v8s*)Wh;
      const v8s* WlF = (const v8s*)Wl_;
      v8s ah0 = AhF[(wave * 2 + 0) * 64 + lane];
      v8s ah1 = AhF[(wave * 2 + 1) * 64 + lane];
      v8s al0 = AlF[(wave * 2 + 0) * 64 + lane];
      v8s al1 = AlF[(wave * 2 + 1) * 64 + lane];
#pragma unroll
      for (int c = 0; c < 8; ++c) {
        v8s bh = WhF[c * 64 + lane];
        v8s bl = WlF[c * 64 + lane];
        acc[c] = __builtin_amdgcn_mfma_f32_16x16x32_bf16(ah0, bh, acc[c], 0, 0, 0);
        acc[c] = __builtin_amdgcn_mfma_f32_16x16x32_bf16(al0, bh, acc[c], 0, 0, 0);
        acc[c] = __builtin_amdgcn_mfma_f32_16x16x32_bf16(ah0, bl, acc[c], 0, 0, 0);
        acc[8 + c] = __builtin_amdgcn_mfma_f32_16x16x32_bf16(ah1, bh, acc[8 + c], 0, 0, 0);
        acc[8 + c] = __builtin_amdgcn_mfma_f32_16x16x32_bf16(al1, bh, acc[8 + c], 0, 0, 0);
        acc[8 + c] = __builtin_amdgcn_mfma_f32_16x16x32_bf16(ah1, bl, acc[8 + c], 0, 0, 0);
      }
    }
  }

  // --- epilogue: bias + activation, fp32 stores (+ optional bf16 image) ---
  float bv[8];
#pragma unroll
  for (int c = 0; c < 8; ++c) bv[c] = bias[c * 16 + m];
#pragma unroll
  for (int tr = 0; tr < 2; ++tr) {
#pragma unroll
    for (int c = 0; c < 8; ++c) {
      v4f a = acc[tr * 8 + c];
#pragma unroll
      for (int i = 0; i < 4; ++i) {
        int row = block_row + wave * 32 + tr * 16 + q * 4 + i;
        if (row < N) {
          float v = a[i] + bv[c];
          if (RELU) v = fmaxf(v, 0.f);
          out[(size_t)row * H + c * 16 + m] = v;
          if (hb_out) hb_out[(size_t)row * H + c * 16 + m] = bf16_rne(v);
        }
      }
    }
  }
}

// ---------------- launch ----------------

extern "C" void kernel_launch(void* const* d_in, const int* in_sizes, int n_in,
                              void* d_out, int out_size, void* d_ws, size_t ws_size,
                              hipStream_t stream) {
  const int* node_id = (const int*)d_in[0];
  const int* edge_index = (const int*)d_in[1];
  const float* emb = (const float*)d_in[2];
  const float* W1l = (const float*)d_in[3];
  const float* b1l = (const float*)d_in[4];
  const float* W1r = (const float*)d_in[5];
  const float* W2l = (const float*)d_in[6];
  const float* b2l = (const float*)d_in[7];
  const float* W2r = (const float*)d_in[8];
  const float* W3l = (const float*)d_in[9];
  const float* b3l = (const float*)d_in[10];
  const float* W3r = (const float*)d_in[11];

  int N = in_sizes[0];
  int E = in_sizes[1] / 2;
  const int* src = edge_index;
  const int* dst = edge_index + E;

  char* w = (char*)d_ws;
  auto alloc = [&](size_t bytes) {
    void* p = (void*)w;
    w += (bytes + 255) & ~(size_t)255;
    return p;
  };
  int* deg = (int*)alloc((size_t)N * 4);
  int* cursor = (int*)alloc((size_t)N * 4);
  int* row_start = (int*)alloc((size_t)N * 4);
  int* incl = (int*)alloc((size_t)N * 4);
  int* blk_sum = (int*)alloc(1024);
  int* blk_off = (int*)alloc(1024);
  int* csr_src = (int*)alloc((size_t)E * 4);
  float* hbuf = (float*)alloc((size_t)N * H * 4);
  unsigned short* hb = (unsigned short*)alloc((size_t)N * H * 2);
  unsigned short* agh = (unsigned short*)alloc((size_t)N * H * 2);
  unsigned short* agl = (unsigned short*)alloc((size_t)N * H * 2);
  unsigned short* whi = (unsigned short*)alloc(6 * 16384 * 2);
  unsigned short* wlo = (unsigned short*)alloc(6 * 16384 * 2);

  hipMemsetAsync(deg, 0, (size_t)N * 4, stream);
  hipMemsetAsync(cursor, 0, (size_t)N * 4, stream);

  hist_kernel<<<(E + 255) / 256, 256, 0, stream>>>(dst, deg, E);
  int SB = (N + 1023) / 1024;
  scan1_kernel<<<SB, 1024, 0, stream>>>(deg, incl, blk_sum, N);
  scan2_kernel<<<1, 256, 0, stream>>>(blk_sum, blk_off, SB);
  rowstart_kernel<<<(N + 255) / 256, 256, 0, stream>>>(incl, deg, blk_off, row_start, N);
  fill_kernel<<<(E + 255) / 256, 256, 0, stream>>>(src, dst, row_start, cursor, csr_src, E);

  gather_kernel<<<(N * 32 + 255) / 256, 256, 0, stream>>>(emb, node_id, hbuf, hb, N);
  // planes order: [W1l, W1r, W2l, W2r, W3l, W3r]
  wsplit_kernel<<<96, 256, 0, stream>>>(W1l, W1r, W2l, W2r, W3l, W3r, whi, wlo);

  int gag = (N + 3) / 4;
  int ggm = (N + 127) / 128;

  // layer 1
  aggregate_kernel<<<gag, 256, 0, stream>>>(hb, csr_src, row_start, deg, agh, agl, N);
  gemm_mfma<1><<<ggm, 256, 0, stream>>>(agh, agl, hbuf,
                                        whi + 0 * 16384, wlo + 0 * 16384,
                                        whi + 1 * 16384, wlo + 1 * 16384, b1l,
                                        hbuf, hb, N);

  // layer 2
  aggregate_kernel<<<gag, 256, 0, stream>>>(hb, csr_src, row_start, deg, agh, agl, N);
  gemm_mfma<1><<<ggm, 256, 0, stream>>>(agh, agl, hbuf,
                                        whi + 2 * 16384, wlo + 2 * 16384,
                                        whi + 3 * 16384, wlo + 3 * 16384, b2l,
                                        hbuf, hb, N);

  // layer 3 -> fp32 d_out
  aggregate_kernel<<<gag, 256, 0, stream>>>(hb, csr_src, row_start, deg, agh, agl, N);
  gemm_mfma<0><<<ggm, 256, 0, stream>>>(agh, agl, hbuf,
                                        whi + 4 * 16384, wlo + 4 * 16384,
                                        whi + 5 * 16384, wlo + 5 * 16384, b3l,
                                        (float*)d_out, nullptr, N);
}